// Round 1
// baseline (826.440 us; speedup 1.0000x reference)
//
#include <hip/hip_runtime.h>
#include <math.h>

#define NN 10000
#define IN_DIM 1000
#define HID 256
#define OUT_DIM 2

// ---------------- degree / CSR build ----------------

__global__ void k_zero_deg(int* deg, int n) {
    int i = blockIdx.x * 256 + threadIdx.x;
    if (i < n) deg[i] = 0;
}

__global__ void k_count(const int* __restrict__ dst, int E, int* __restrict__ deg) {
    int e = blockIdx.x * 256 + threadIdx.x;
    if (e < E) atomicAdd(&deg[dst[e]], 1);
}

__global__ void k_dinv(const int* __restrict__ deg, float* __restrict__ dinv, int n) {
    int i = blockIdx.x * 256 + threadIdx.x;
    if (i < n) dinv[i] = rsqrtf(1.0f + (float)deg[i]);   // self-loop => deg>=1
}

// single-block exclusive scan of deg -> offs, cursor
__global__ void k_scan(const int* __restrict__ deg, int* __restrict__ offs,
                       int* __restrict__ cursor, int n, int E) {
    __shared__ int part[256];
    int t = threadIdx.x;
    int chunk = (n + 255) / 256;
    int lo = t * chunk;
    int hi = lo + chunk; if (hi > n) hi = n;
    int s = 0;
    for (int i = lo; i < hi; i++) s += deg[i];
    part[t] = s;
    __syncthreads();
    if (t == 0) {
        int run = 0;
        for (int i = 0; i < 256; i++) { int tmp = part[i]; part[i] = run; run += tmp; }
    }
    __syncthreads();
    int base = part[t];
    for (int i = lo; i < hi; i++) { offs[i] = base; cursor[i] = base; base += deg[i]; }
    if (t == 0) offs[n] = E;
}

__global__ void k_fill(const int* __restrict__ src, const int* __restrict__ dst, int E,
                       int* __restrict__ cursor, int* __restrict__ csr) {
    int e = blockIdx.x * 256 + threadIdx.x;
    if (e < E) {
        int p = atomicAdd(&cursor[dst[e]], 1);
        csr[p] = src[e];
    }
}

// ---------------- GEMM1: xw1 = features @ W1  (fp32, LDS tiled) ----------------
// BM=128, BN=64, BK=8, 256 threads (16x16), 8x4 micro-tile.

#define BM 128
#define BN 64
#define BK 8

__global__ __launch_bounds__(256) void k_gemm1(const float* __restrict__ A,
                                               const float* __restrict__ B,
                                               float* __restrict__ C,
                                               int M, int K, int N) {
    __shared__ float As[BK][BM + 4];   // pitch 132 (16B-aligned, breaks bank stride)
    __shared__ float Bs[BK][BN];
    int tid = threadIdx.x;
    int tx = tid & 15, ty = tid >> 4;
    int row0 = blockIdx.y * BM, col0 = blockIdx.x * BN;

    float acc[8][4];
    #pragma unroll
    for (int i = 0; i < 8; i++)
        #pragma unroll
        for (int j = 0; j < 4; j++) acc[i][j] = 0.0f;

    for (int k0 = 0; k0 < K; k0 += BK) {
        // stage A: 128x8 elems, 4 per thread
        {
            int kk = tid & 7, m = tid >> 3;
            #pragma unroll
            for (int r = 0; r < 4; r++, m += 32) {
                int row = row0 + m;
                As[kk][m] = (row < M) ? A[row * K + k0 + kk] : 0.0f;
            }
        }
        // stage B: 8x64 elems, 2 per thread
        {
            int bn = tid & 63, kk = tid >> 6;
            Bs[kk][bn]     = B[(k0 + kk) * N + col0 + bn];
            Bs[kk + 4][bn] = B[(k0 + kk + 4) * N + col0 + bn];
        }
        __syncthreads();
        #pragma unroll
        for (int kk = 0; kk < BK; kk++) {
            float4 a0 = *(const float4*)&As[kk][ty * 8];
            float4 a1 = *(const float4*)&As[kk][ty * 8 + 4];
            float4 b  = *(const float4*)&Bs[kk][tx * 4];
            float am[8] = {a0.x, a0.y, a0.z, a0.w, a1.x, a1.y, a1.z, a1.w};
            float bn4[4] = {b.x, b.y, b.z, b.w};
            #pragma unroll
            for (int i = 0; i < 8; i++)
                #pragma unroll
                for (int j = 0; j < 4; j++)
                    acc[i][j] += am[i] * bn4[j];
        }
        __syncthreads();
    }
    #pragma unroll
    for (int i = 0; i < 8; i++) {
        int row = row0 + ty * 8 + i;
        if (row < M) {
            float4 v = {acc[i][0], acc[i][1], acc[i][2], acc[i][3]};
            *(float4*)&C[row * N + col0 + tx * 4] = v;
        }
    }
}

// ---------------- aggregation 1 + bias + relu (block per node, thread per dim) -------

__global__ __launch_bounds__(256) void k_agg1(const float* __restrict__ xw1,
                                              const int* __restrict__ offs,
                                              const int* __restrict__ csr,
                                              const float* __restrict__ dinv,
                                              const float* __restrict__ b1,
                                              float* __restrict__ h) {
    int i = blockIdx.x;
    int t = threadIdx.x;
    float di = dinv[i];
    float acc = di * xw1[i * HID + t];          // self-loop (factor di applied at end)
    int s0 = offs[i], s1 = offs[i + 1];
    for (int e = s0; e < s1; e++) {
        int s = csr[e];
        acc += dinv[s] * xw1[s * HID + t];
    }
    float v = di * acc + b1[t];
    h[i * HID + t] = fmaxf(v, 0.0f);
}

// ---------------- GEMM2 (wave per row) + self-loop epilogue into emb ----------------

__global__ __launch_bounds__(256) void k_gemm2(const float* __restrict__ h,
                                               const float* __restrict__ W2,
                                               const float* __restrict__ b2,
                                               const float* __restrict__ dinv,
                                               float* __restrict__ hw2,
                                               float* __restrict__ emb, int n) {
    int w = threadIdx.x >> 6, l = threadIdx.x & 63;
    int row = blockIdx.x * 4 + w;
    if (row >= n) return;
    float4 hv = *(const float4*)&h[row * HID + l * 4];
    // W2 row-major [256][2]; lane l covers k=4l..4l+3 -> floats 8l..8l+7
    float4 w0 = *(const float4*)&W2[l * 8];
    float4 w1 = *(const float4*)&W2[l * 8 + 4];
    float a0 = hv.x * w0.x + hv.y * w0.z + hv.z * w1.x + hv.w * w1.z;
    float a1 = hv.x * w0.y + hv.y * w0.w + hv.z * w1.y + hv.w * w1.w;
    #pragma unroll
    for (int off = 32; off; off >>= 1) {
        a0 += __shfl_down(a0, off);
        a1 += __shfl_down(a1, off);
    }
    if (l == 0) {
        hw2[row * 2] = a0;
        hw2[row * 2 + 1] = a1;
        float di = dinv[row];
        emb[row * 2]     = di * di * a0 + b2[0];
        emb[row * 2 + 1] = di * di * a1 + b2[1];
    }
}

// ---------------- aggregation 2 (wave per node, accumulate into emb) ----------------

__global__ __launch_bounds__(256) void k_agg2(const float* __restrict__ hw2,
                                              const int* __restrict__ offs,
                                              const int* __restrict__ csr,
                                              const float* __restrict__ dinv,
                                              float* __restrict__ emb, int n) {
    int w = threadIdx.x >> 6, l = threadIdx.x & 63;
    int i = blockIdx.x * 4 + w;
    if (i >= n) return;
    int s0 = offs[i], s1 = offs[i + 1];
    float a0 = 0.0f, a1 = 0.0f;
    for (int e = s0 + l; e < s1; e += 64) {
        int s = csr[e];
        float ds = dinv[s];
        a0 += ds * hw2[s * 2];
        a1 += ds * hw2[s * 2 + 1];
    }
    #pragma unroll
    for (int off = 32; off; off >>= 1) {
        a0 += __shfl_down(a0, off);
        a1 += __shfl_down(a1, off);
    }
    if (l == 0) {
        float di = dinv[i];
        emb[i * 2]     += di * a0;   // only this wave touches node i
        emb[i * 2 + 1] += di * a1;
    }
}

// ---------------- q = 1/(1 + 0.5*dist(e_i, e_j)), row-major [n][n] ----------------

__global__ __launch_bounds__(256) void k_q(const float* __restrict__ emb,
                                           float* __restrict__ q, int n) {
    int i = blockIdx.y;
    int j0 = (blockIdx.x * 256 + threadIdx.x) * 4;
    if (j0 >= n) return;
    float2 ei = *(const float2*)&emb[i * 2];
    float4 e01 = *(const float4*)&emb[j0 * 2];
    float4 e23 = *(const float4*)&emb[j0 * 2 + 4];
    float4 out;
    {
        float dx = ei.x - e01.x, dy = ei.y - e01.y;
        out.x = 1.0f / (1.0f + 0.5f * sqrtf(dx * dx + dy * dy));
    }
    {
        float dx = ei.x - e01.z, dy = ei.y - e01.w;
        out.y = 1.0f / (1.0f + 0.5f * sqrtf(dx * dx + dy * dy));
    }
    {
        float dx = ei.x - e23.x, dy = ei.y - e23.y;
        out.z = 1.0f / (1.0f + 0.5f * sqrtf(dx * dx + dy * dy));
    }
    {
        float dx = ei.x - e23.z, dy = ei.y - e23.w;
        out.w = 1.0f / (1.0f + 0.5f * sqrtf(dx * dx + dy * dy));
    }
    *(float4*)&q[(size_t)i * n + j0] = out;
}

// ---------------- launcher ----------------

extern "C" void kernel_launch(void* const* d_in, const int* in_sizes, int n_in,
                              void* d_out, int out_size, void* d_ws, size_t ws_size,
                              hipStream_t stream) {
    const float* features = (const float*)d_in[0];
    const int*   edge_index = (const int*)d_in[1];
    const float* W1 = (const float*)d_in[2];
    const float* b1 = (const float*)d_in[3];
    const float* W2 = (const float*)d_in[4];
    const float* b2 = (const float*)d_in[5];

    const int n = NN;
    const int E = in_sizes[1] / 2;
    const int* src = edge_index;
    const int* dst = edge_index + E;

    char* ws = (char*)d_ws;
    int*   deg    = (int*)ws;   ws += 40000;
    float* dinv   = (float*)ws; ws += 40000;
    int*   offs   = (int*)ws;   ws += 40016;          // n+1, padded to 16B
    int*   cursor = (int*)ws;   ws += 40000;
    int*   csr    = (int*)ws;   ws += (size_t)E * 4;  // 640 KB
    float* xw1    = (float*)ws; ws += (size_t)NN * HID * 4;   // 10.24 MB
    float* h      = (float*)ws; ws += (size_t)NN * HID * 4;   // 10.24 MB
    float* hw2    = (float*)ws; ws += (size_t)NN * OUT_DIM * 4;

    float* emb = (float*)d_out;                 // [n,2]
    float* q   = (float*)d_out + (size_t)n * OUT_DIM;  // [n,n]

    k_zero_deg<<<(n + 255) / 256, 256, 0, stream>>>(deg, n);
    k_count<<<(E + 255) / 256, 256, 0, stream>>>(dst, E, deg);
    k_dinv<<<(n + 255) / 256, 256, 0, stream>>>(deg, dinv, n);
    k_scan<<<1, 256, 0, stream>>>(deg, offs, cursor, n, E);
    k_fill<<<(E + 255) / 256, 256, 0, stream>>>(src, dst, E, cursor, csr);

    k_gemm1<<<dim3(HID / BN, (n + BM - 1) / BM), 256, 0, stream>>>(
        features, W1, xw1, n, IN_DIM, HID);
    k_agg1<<<n, HID, 0, stream>>>(xw1, offs, csr, dinv, b1, h);
    k_gemm2<<<(n + 3) / 4, 256, 0, stream>>>(h, W2, b2, dinv, hw2, emb, n);
    k_agg2<<<(n + 3) / 4, 256, 0, stream>>>(hw2, offs, csr, dinv, emb, n);

    k_q<<<dim3((n + 1023) / 1024, n), 256, 0, stream>>>(emb, q, n);
}